// Round 7
// baseline (1881.392 us; speedup 1.0000x reference)
//
#include <hip/hip_runtime.h>
#include <math.h>

#define TT 1024
#define KK 128
#define NB 16          // batches per block (= per consumer wave)
#define XP 20          // xbuf batch-stride pad (conflict-free b64 reads)
#define CH 8           // timesteps per staged chunk
#define NCH (TT / CH)  // 128
#define LN2 0.69314718055994531f

typedef float f4v __attribute__((ext_vector_type(4)));
typedef short s8v __attribute__((ext_vector_type(8)));
#define MFMA16 __builtin_amdgcn_mfma_f32_16x16x32_bf16

__global__ void zero_out_kernel(float* out) { out[0] = 0.0f; }

__device__ __forceinline__ unsigned short bf16rne(float x) {
    unsigned u = __float_as_uint(x);
    return (unsigned short)((u + 0x7FFFu + ((u >> 16) & 1u)) >> 16);
}
__device__ __forceinline__ float lobf(unsigned u) { return __uint_as_float(u << 16); }
__device__ __forceinline__ float hibf(unsigned u) { return __uint_as_float(u & 0xFFFF0000u); }

// A-layout LDS index: g = state>>3 (0..15), row m (0..15), +i3 = state&7.
// m-swizzle by g makes the consumer's b128 reads 2-way (free).
__device__ __forceinline__ int AI(int g, int m) { return (g * 17 + ((m + g) & 15)) * 8; }

// B-fragment of exp(trans), 16x16x32 bf16 (layout verified in round 6):
// B[k][n]: n = lane&15, k = (lane>>4)*8 + i.  Global i = 32*kt + k, j = 16*nt + n.
__device__ __forceinline__ s8v load_E(const float* __restrict__ trans, int kt, int nt, int lane) {
    s8v f;
    const float* base = trans + (size_t)(32 * kt + ((lane >> 4) << 3)) * KK + 16 * nt + (lane & 15);
#pragma unroll
    for (int i = 0; i < 8; ++i) f[i] = (short)bf16rne(expf(base[(size_t)i * KK]));
    return f;
}

// Producers: stage chunk c emissions as X=exp(e) bf16 into [t][j][b(pad XP)] + mask [t][b].
__device__ __forceinline__ void stage_chunk(const float* __restrict__ binp0,
                                            const int* __restrict__ bmask0,
                                            int c, unsigned short* xb, float* mb,
                                            int tid, int nthr) {
    const int NF4 = CH * NB * KK / 4;  // 4096 float4s
    for (int f = tid; f < NF4; f += nthr) {
        int j4 = f & 31;
        int t  = (f >> 5) & 7;
        int b  = f >> 8;
        float4 e = *(const float4*)(binp0 + ((size_t)b * TT + (size_t)c * CH + t) * KK + 4 * j4);
        int base = (t * KK + 4 * j4) * XP + b;
        xb[base         ] = bf16rne(__expf(e.x));
        xb[base + XP    ] = bf16rne(__expf(e.y));
        xb[base + 2 * XP] = bf16rne(__expf(e.z));
        xb[base + 3 * XP] = bf16rne(__expf(e.w));
    }
    for (int i = tid; i < CH * NB; i += nthr) {
        int b = i & 15, t = i >> 4;
        mb[t * NB + b] = (float)bmask0[(size_t)b * TT + (size_t)c * CH + t];
    }
}

// D->A transpose write: lane holds 4 batches (rows r0..r0+3) at state j=16nt+c.
// Pack by batch, exchange with XOR-1 neighbor, emit state-pair b32 writes.
__device__ __forceinline__ void writeA(unsigned short* aw, int nt, int l,
                                       float v0, float v1, float v2, float v3) {
    int c  = l & 15;
    int r0 = (l >> 4) << 2;
    unsigned u0 = __float_as_uint(v0) + 0x8000u;
    unsigned u1 = __float_as_uint(v1) + 0x8000u;
    unsigned u2 = __float_as_uint(v2) + 0x8000u;
    unsigned u3 = __float_as_uint(v3) + 0x8000u;
    unsigned P01 = (u1 & 0xFFFF0000u) | (u0 >> 16);   // [r0+1 | r0] @ state c
    unsigned P23 = (u3 & 0xFFFF0000u) | (u2 >> 16);   // [r0+3 | r0+2] @ state c
    bool odd = (l & 1);
    unsigned send = odd ? P01 : P23;
    unsigned got  = (unsigned)__shfl_xor((int)send, 1);
    unsigned oA = !odd ? ((P01 & 0xFFFFu) | (got << 16))
                       : ((got & 0xFFFFu) | (P23 << 16));
    unsigned oB = !odd ? ((P01 >> 16) | (got & 0xFFFF0000u))
                       : ((got >> 16) | (P23 & 0xFFFF0000u));
    int j0 = 16 * nt + (c & ~1);
    int g  = j0 >> 3;
    int rA = !odd ? r0 : (r0 + 2);
    *(unsigned*)&aw[AI(g, rA    ) + (j0 & 7)] = oA;
    *(unsigned*)&aw[AI(g, rA + 1) + (j0 & 7)] = oB;
}

#define DECL_EK(KT) s8v E##KT##0, E##KT##1, E##KT##2, E##KT##3, E##KT##4, E##KT##5, E##KT##6, E##KT##7;
#define LOAD_EK(KT) { E##KT##0 = load_E(trans, KT, 0, l); E##KT##1 = load_E(trans, KT, 1, l); \
    E##KT##2 = load_E(trans, KT, 2, l); E##KT##3 = load_E(trans, KT, 3, l); \
    E##KT##4 = load_E(trans, KT, 4, l); E##KT##5 = load_E(trans, KT, 5, l); \
    E##KT##6 = load_E(trans, KT, 6, l); E##KT##7 = load_E(trans, KT, 7, l); }

#define CHAIN(NT) f4v acc##NT = MFMA16(a0, E0##NT, (f4v){0.f,0.f,0.f,0.f}, 0,0,0); \
    acc##NT = MFMA16(a1, E1##NT, acc##NT, 0,0,0); \
    acc##NT = MFMA16(a2, E2##NT, acc##NT, 0,0,0); \
    acc##NT = MFMA16(a3, E3##NT, acc##NT, 0,0,0);

#define EPI(NT, PP) { \
    unsigned long long xw8 = *(const unsigned long long*)&xb[(s * KK + 16 * NT + c_) * XP + r0_]; \
    unsigned xlo = (unsigned)xw8, xhi = (unsigned)(xw8 >> 32); \
    float t0 = acc##NT[0] * lobf(xlo); \
    float t1 = acc##NT[1] * hibf(xlo); \
    float t2 = acc##NT[2] * lobf(xhi); \
    float t3 = acc##NT[3] * hibf(xhi); \
    float v0 = ((mf.x != 0.f) ? t0 : PP[0]) * sc0; \
    float v1 = ((mf.y != 0.f) ? t1 : PP[1]) * sc1; \
    float v2 = ((mf.z != 0.f) ? t2 : PP[2]) * sc2; \
    float v3 = ((mf.w != 0.f) ? t3 : PP[3]) * sc3; \
    PP[0] = v0; PP[1] = v1; PP[2] = v2; PP[3] = v3; \
    writeA(aw, NT, l, v0, v1, v2, v3); }

#define INIT_NT(NT, PP) { \
    unsigned long long xw8 = *(const unsigned long long*)&xbuf[0][(16 * NT + c_) * XP + r0_]; \
    unsigned xlo = (unsigned)xw8, xhi = (unsigned)(xw8 >> 32); \
    PP[0] = lobf(xlo); PP[1] = hibf(xlo); PP[2] = lobf(xhi); PP[3] = hibf(xhi); \
    writeA(abuf[0], NT, l, PP[0], PP[1], PP[2], PP[3]); }

// 16 blocks x 256 threads. Wave 0: 16-batch MFMA forward recursion.
// Waves 1-3: producers staging X=exp(emissions) a chunk ahead.
__global__ __launch_bounds__(256, 1) void crf_kernel(
    const float* __restrict__ inputs,      // B*T*K fp32
    const float* __restrict__ trans,       // K*K fp32
    const int* __restrict__ tags,          // B*T int32 view
    const int* __restrict__ mask,          // B*T int32
    float* __restrict__ out) {
    __shared__ unsigned short xbuf[2][CH * KK * XP];   // 80 KB
    __shared__ float mfb[2][CH * NB];                  // 1 KB
    __shared__ unsigned short abuf[2][2176];           // 8.5 KB (p, bf16, A-layout)
    __shared__ float dend[NB];

    const int tid = threadIdx.x;
    const int l   = tid & 63;
    const int wv  = tid >> 6;
    const int b0  = blockIdx.x * NB;
    const int c_  = l & 15;
    const int q_  = l >> 4;
    const int r0_ = q_ << 2;

    const float* binp0 = inputs + (size_t)b0 * TT * KK;
    const int* bmask0  = mask + (size_t)b0 * TT;

    // all 4 waves stage chunk 0
    stage_chunk(binp0, bmask0, 0, xbuf[0], mfb[0], tid, 256);

    DECL_EK(0) DECL_EK(1) DECL_EK(2) DECL_EK(3)
    f4v pp0, pp1, pp2, pp3, pp4, pp5, pp6, pp7;
    int m0 = 0, m1 = 0, m2 = 0, m3 = 0;

    if (wv == 0) { LOAD_EK(0) LOAD_EK(1) LOAD_EK(2) LOAD_EK(3) }
    __syncthreads();   // xbuf[0]/mfb[0] ready

    if (wv == 0) {     // t = 0: alpha0 = emit[0] -> p = X[0]
        INIT_NT(0, pp0) INIT_NT(1, pp1) INIT_NT(2, pp2) INIT_NT(3, pp3)
        INIT_NT(4, pp4) INIT_NT(5, pp5) INIT_NT(6, pp6) INIT_NT(7, pp7)
    }

    for (int c = 0; c < NCH; ++c) {
        if (wv == 0) {
            const unsigned short* xb = xbuf[c & 1];
            const float* mb = mfb[c & 1];
            const int s0 = (c == 0) ? 1 : 0;
            for (int s = s0; s < CH; ++s) {
                const int t = c * CH + s;
                const unsigned short* ar = abuf[(t - 1) & 1];
                unsigned short* aw = abuf[t & 1];
                s8v a0 = *(const s8v*)&ar[AI(q_,      c_)];
                s8v a1 = *(const s8v*)&ar[AI(4 + q_,  c_)];
                s8v a2 = *(const s8v*)&ar[AI(8 + q_,  c_)];
                s8v a3 = *(const s8v*)&ar[AI(12 + q_, c_)];
                CHAIN(0) CHAIN(1) CHAIN(2) CHAIN(3)
                CHAIN(4) CHAIN(5) CHAIN(6) CHAIN(7)
                // per-batch exact-pow2 renorm from D column 0 (z[r][0])
                float sc0, sc1, sc2, sc3;
                {
                    int src = l & 48;
#define RN(R, SCV, MV) { float zz = __shfl(acc0[R], src); \
    int E0 = ((__float_as_int(zz) >> 23) & 255) - 127; \
    MV += E0; SCV = __uint_as_float((unsigned)(127 - E0) << 23); }
                    RN(0, sc0, m0) RN(1, sc1, m1) RN(2, sc2, m2) RN(3, sc3, m3)
#undef RN
                }
                float4 mf = *(const float4*)&mb[s * NB + r0_];
                EPI(0, pp0) EPI(1, pp1) EPI(2, pp2) EPI(3, pp3)
                EPI(4, pp4) EPI(5, pp5) EPI(6, pp6) EPI(7, pp7)
            }
        } else {
            if (c + 1 < NCH)
                stage_chunk(binp0, bmask0, c + 1, xbuf[(c + 1) & 1], mfb[(c + 1) & 1],
                            tid - 64, 192);
        }
        __syncthreads();
    }

    // ---- denominator per batch: m*ln2 + log(sum_j p_j) ----
    if (wv == 0) {
        f4v ps = ((pp0 + pp1) + (pp2 + pp3)) + ((pp4 + pp5) + (pp6 + pp7));
#pragma unroll
        for (int o = 1; o < 16; o <<= 1) {
            ps[0] += __shfl_xor(ps[0], o);
            ps[1] += __shfl_xor(ps[1], o);
            ps[2] += __shfl_xor(ps[2], o);
            ps[3] += __shfl_xor(ps[3], o);
        }
        if (c_ == 0) {
            dend[r0_ + 0] = (float)m0 * LN2 + logf(ps[0]);
            dend[r0_ + 1] = (float)m1 * LN2 + logf(ps[1]);
            dend[r0_ + 2] = (float)m2 * LN2 + logf(ps[2]);
            dend[r0_ + 3] = (float)m3 * LN2 + logf(ps[3]);
        }
    }
    __syncthreads();

    // ---- numerator: 16 threads per batch ----
    {
        int r = tid >> 4, seg = tid & 15;
        const float* bi = inputs + (size_t)(b0 + r) * TT * KK;
        const int* tg = tags + (size_t)(b0 + r) * TT;
        const int* mk = mask + (size_t)(b0 + r) * TT;
        float np = 0.f, mp = 0.f;
        for (int u = 0; u < TT / 16; ++u) {
            int t = seg * (TT / 16) + u;
            int tgt = tg[t];
            float mf = (float)mk[t];
            mp += mf;
            if (t < TT - 1) {
                np += trans[tgt * KK + tg[t + 1]] * (float)mk[t + 1];
                np += bi[(size_t)t * KK + tgt] * mf;
            }
        }
#pragma unroll
        for (int o = 1; o < 16; o <<= 1) { np += __shfl_xor(np, o); mp += __shfl_xor(mp, o); }
        if (seg == 0) {
            int last = (int)mp - 1;
            float num = np + bi[(size_t)(TT - 1) * KK + tg[last]] * (float)mk[TT - 1];
            atomicAdd(out, num - dend[r]);
        }
    }
}

extern "C" void kernel_launch(void* const* d_in, const int* in_sizes, int n_in,
                              void* d_out, int out_size, void* d_ws, size_t ws_size,
                              hipStream_t stream) {
    const float* inputs = (const float*)d_in[0];
    const float* trans  = (const float*)d_in[1];
    const int* tagsp    = (const int*)d_in[2];
    const int* maskp    = (const int*)d_in[3];
    float* out          = (float*)d_out;
    zero_out_kernel<<<1, 1, 0, stream>>>(out);
    crf_kernel<<<256 / NB, 256, 0, stream>>>(inputs, trans, tagsp, maskp, out);
}